// Round 1
// baseline (5968.266 us; speedup 1.0000x reference)
//
#include <hip/hip_runtime.h>
#include <math.h>

#define BB 1024
#define LL 256
#define MM 256
#define HH 64

// ws float offsets
#define OFF_TOKPROJ 0        // 64*192
#define OFF_WRT     12288    // 64*192  (gru_wih[:,64:128] transposed)
#define OFF_WHHT    24576    // 64*192
#define OFF_LB      36864    // 128 (lstm_bih+lstm_bhh)
#define OFF_LWIHT   36992    // 64*128
#define OFF_LWHHT   45184    // 32*128
#define OFF_A       49280    // 64*64
#define OFF_AVEC    53376    // 64
#define OFF_VWT     53440    // 64*64
#define OFF_HEADT   57536    // 64*64
#define OFF_H       61632    // 1024*64
#define OFF_PX      127168   // 4*1024*128
#define OFF_ACC     651456   // 256 x u64  (512 floats)

#define ACC_THRESH (512ULL << 30)   // mean > 0.5  <=>  sum(prob*2^30) > 512*2^30

__device__ __forceinline__ float sigf(float x) { return 1.f / (1.f + expf(-x)); }

// ---------------- prep: transposes, fused tables, state init ----------------
__global__ __launch_bounds__(64) void prep_k(
    const float* __restrict__ embed, const float* __restrict__ gwih,
    const float* __restrict__ gwhh, const float* __restrict__ gbih,
    const float* __restrict__ qw, const float* __restrict__ qb,
    const float* __restrict__ kw, const float* __restrict__ vw,
    const float* __restrict__ lwih, const float* __restrict__ lwhh,
    const float* __restrict__ lbih, const float* __restrict__ lbhh,
    const float* __restrict__ hw, float* __restrict__ ws)
{
    int blk = blockIdx.x, l = threadIdx.x;
    float* tokproj = ws + OFF_TOKPROJ;
    float* WrT = ws + OFF_WRT;
    float* WhhT = ws + OFF_WHHT;
    float* lb = ws + OFF_LB;
    float* lwihT = ws + OFF_LWIHT;
    float* lwhhT = ws + OFF_LWHHT;
    float* A = ws + OFF_A;
    float* avec = ws + OFF_AVEC;
    float* vwT = ws + OFF_VWT;
    float* headT = ws + OFF_HEADT;
    float* Hst = ws + OFF_H;
    unsigned long long* acc = (unsigned long long*)(ws + OFF_ACC);

    if (blk < 64) {
        int v = blk;
        for (int j = l; j < 192; j += 64) {
            float s = gbih[j];
            for (int d = 0; d < 64; ++d) s += embed[v * 64 + d] * gwih[j * 128 + d];
            tokproj[v * 192 + j] = s;
        }
    } else if (blk < 128) {
        int d = blk - 64;
        for (int j = l; j < 192; j += 64) {
            WrT[d * 192 + j] = gwih[j * 128 + 64 + d];
            WhhT[d * 192 + j] = gwhh[j * 64 + d];
        }
        for (int j = l; j < 128; j += 64) lwihT[d * 128 + j] = lwih[j * 64 + d];
        if (d < 32) for (int j = l; j < 128; j += 64) lwhhT[d * 128 + j] = lwhh[j * 32 + d];
        vwT[d * 64 + l] = vw[l * 64 + d];
        headT[d * 64 + l] = hw[l * 64 + d];
    } else if (blk < 192) {
        int d = blk - 128;
        float s = 0.f;
        for (int e = 0; e < 64; ++e) s += qw[e * 64 + d] * kw[e * 64 + l];
        A[d * 64 + l] = s * 0.125f;   // scale = 1/sqrt(64)
    } else if (blk == 192) {
        float s = 0.f;
        for (int e = 0; e < 64; ++e) s += qb[e] * kw[e * 64 + l];
        avec[l] = s * 0.125f;
        lb[l] = lbih[l] + lbhh[l];
        lb[64 + l] = lbih[64 + l] + lbhh[64 + l];
        for (int i = l; i < 256; i += 64) acc[i] = 0ULL;
    } else {
        int base = (blk - 193) * 1024;
        for (int i = base + l; i < base + 1024; i += 64) Hst[i] = 0.f;
    }
}

// ---------------- one timestep: attn(t-1) -> GRU(t) -> trigger(t) ----------
__global__ __launch_bounds__(64) void step_k(
    int t,
    const int* __restrict__ seq, const float* __restrict__ memory,
    const float* __restrict__ gbhh, const float* __restrict__ vb,
    const float* __restrict__ tw, const float* __restrict__ tb,
    float* __restrict__ ws)
{
    int b = blockIdx.x, l = threadIdx.x;
    const float* tokproj = ws + OFF_TOKPROJ;
    const float* WrT = ws + OFF_WRT;
    const float* WhhT = ws + OFF_WHHT;
    const float* lb = ws + OFF_LB;
    const float* lwihT = ws + OFF_LWIHT;
    const float* lwhhT = ws + OFF_LWHHT;
    const float* A = ws + OFF_A;
    const float* avec = ws + OFF_AVEC;
    const float* vwT = ws + OFF_VWT;
    float* Hst = ws + OFF_H;
    float* PX = ws + OFF_PX;
    unsigned long long* acc = (unsigned long long*)(ws + OFF_ACC);

    __shared__ float hs[64], rs[64], qs[64], wsm[64], us[64], hhs[32];
    __shared__ float mch[64][65];

    float h = Hst[b * 64 + l];
    hs[l] = h;
    __syncthreads();

    // ---- B phase: retrieved_{t-1} (attention with h_{t-1}) ----
    bool has = false;
    if (t >= 4) has = (acc[t - 1] > ACC_THRESH);

    float retr = 0.f;
    if (has) {
        float qk = avec[l];
        for (int d = 0; d < 64; ++d) qk += hs[d] * A[d * 64 + l];
        qs[l] = qk;
        __syncthreads();

        float Mx = -1e30f, D = 0.f, u = 0.f;   // u: dim l accumulator
        const float* mrow = memory + (size_t)b * MM * HH;
        for (int c = 0; c < 4; ++c) {
            const float* mp = mrow + c * 64 * 64;
            for (int r = 0; r < 64; ++r) mch[r][l] = mp[r * 64 + l];
            __syncthreads();
            // score for m = c*64 + l
            float s = 0.f;
            for (int d = 0; d < 64; ++d) s += qs[d] * mch[l][d];
            float cm = s;
            for (int o = 32; o; o >>= 1) cm = fmaxf(cm, __shfl_xor(cm, o));
            float newM = fmaxf(Mx, cm);
            float fac = expf(Mx - newM);
            float w = expf(s - newM);
            wsm[l] = w;
            float sw = w;
            for (int o = 32; o; o >>= 1) sw += __shfl_xor(sw, o);
            D = D * fac + sw;
            u *= fac;
            __syncthreads();
            for (int m = 0; m < 64; ++m) u += wsm[m] * mch[m][l];
            Mx = newM;
            __syncthreads();
        }
        u /= D;
        us[l] = u;
        __syncthreads();
        float rv = vb[l];
        for (int d = 0; d < 64; ++d) rv += us[d] * vwT[d * 64 + l];
        retr = rv;
    }
    rs[l] = retr;
    __syncthreads();

    // ---- A phase: GRU ----
    int tok = seq[b * LL + t];
    const float* tp = tokproj + tok * 192;
    float gi0 = tp[l], gi1 = tp[64 + l], gi2 = tp[128 + l];
    if (has) {
        for (int d = 0; d < 64; ++d) {
            float s = rs[d];
            gi0 += s * WrT[d * 192 + l];
            gi1 += s * WrT[d * 192 + 64 + l];
            gi2 += s * WrT[d * 192 + 128 + l];
        }
    }
    float gh0 = gbhh[l], gh1 = gbhh[64 + l], gh2 = gbhh[128 + l];
    for (int d = 0; d < 64; ++d) {
        float s = hs[d];
        gh0 += s * WhhT[d * 192 + l];
        gh1 += s * WhhT[d * 192 + 64 + l];
        gh2 += s * WhhT[d * 192 + 128 + l];
    }
    float r = sigf(gi0 + gh0);
    float z = sigf(gi1 + gh1);
    float n = tanhf(gi2 + r * gh2);
    float hn = (1.f - z) * n + z * h;
    Hst[b * 64 + l] = hn;
    __syncthreads();
    hs[l] = hn;
    __syncthreads();

    // ---- LSTM input projection for h_t (reused 4 steps) ----
    float p0 = lb[l], p1 = lb[64 + l];
    for (int d = 0; d < 64; ++d) {
        float s = hs[d];
        p0 += s * lwihT[d * 128 + l];
        p1 += s * lwihT[d * 128 + 64 + l];
    }
    size_t pxoff = (size_t)(t & 3) * BB * 128 + (size_t)b * 128;
    PX[pxoff + l] = p0;
    PX[pxoff + 64 + l] = p1;

    // ---- trigger LSTM over hist (only matters for t >= 3) ----
    if (t >= 3) {
        float hh = 0.f, cc = 0.f;   // lanes 0..31 hold state
        for (int k = 0; k < 4; ++k) {
            float g0, g1;
            if (k == 3) { g0 = p0; g1 = p1; }
            else {
                int slot = (t - 3 + k) & 3;
                size_t po = (size_t)slot * BB * 128 + (size_t)b * 128;
                g0 = PX[po + l];
                g1 = PX[po + 64 + l];
            }
            if (k) {
                for (int d = 0; d < 32; ++d) {
                    float s = hhs[d];
                    g0 += s * lwhhT[d * 128 + l];
                    g1 += s * lwhhT[d * 128 + 64 + l];
                }
            }
            float f_ = __shfl(g0, l + 32);
            float o_ = __shfl(g1, l + 32);
            if (l < 32) {
                float ig = sigf(g0), ff = sigf(f_), gg = tanhf(g1), oo = sigf(o_);
                cc = ff * cc + ig * gg;
                hh = oo * tanhf(cc);
                hhs[l] = hh;
            }
            __syncthreads();
        }
        float pp = (l < 32) ? hh * tw[l] : 0.f;
        for (int o = 32; o; o >>= 1) pp += __shfl_xor(pp, o);
        if (l == 0) {
            float prob = sigf(pp + tb[0]);
            unsigned long long q = (unsigned long long)llrint((double)prob * 1073741824.0);
            atomicAdd(&acc[t], q);
        }
    }
}

// ---------------- epilogue: logits + read_rate ----------------
__global__ __launch_bounds__(64) void epi_k(
    const float* __restrict__ hb, float* __restrict__ ws, float* __restrict__ out)
{
    int b = blockIdx.x, l = threadIdx.x;
    const float* Hst = ws + OFF_H;
    const float* headT = ws + OFF_HEADT;
    const unsigned long long* acc = (const unsigned long long*)(ws + OFF_ACC);
    __shared__ float hs[64];
    hs[l] = Hst[b * 64 + l];
    __syncthreads();
    float s = hb[l];
    for (int d = 0; d < 64; ++d) s += hs[d] * headT[d * 64 + l];
    out[b * 64 + l] = s;
    if (b == 0 && l == 0) {
        int cnt = 0;
        for (int tt = 3; tt < 256; ++tt) cnt += (acc[tt] > ACC_THRESH) ? 1 : 0;
        out[65536] = (float)cnt / 256.f;
    }
}

extern "C" void kernel_launch(void* const* d_in, const int* in_sizes, int n_in,
                              void* d_out, int out_size, void* d_ws, size_t ws_size,
                              hipStream_t stream)
{
    const int*   seq    = (const int*)d_in[0];
    const float* memory = (const float*)d_in[1];
    const float* embed  = (const float*)d_in[2];
    const float* gwih   = (const float*)d_in[3];
    const float* gwhh   = (const float*)d_in[4];
    const float* gbih   = (const float*)d_in[5];
    const float* gbhh   = (const float*)d_in[6];
    const float* qw     = (const float*)d_in[7];
    const float* qb     = (const float*)d_in[8];
    const float* kw     = (const float*)d_in[9];
    // d_in[10] = k_b : cancels in softmax, unused
    const float* vw     = (const float*)d_in[11];
    const float* vb     = (const float*)d_in[12];
    const float* lwih   = (const float*)d_in[13];
    const float* lwhh   = (const float*)d_in[14];
    const float* lbih   = (const float*)d_in[15];
    const float* lbhh   = (const float*)d_in[16];
    const float* tw     = (const float*)d_in[17];
    const float* tb     = (const float*)d_in[18];
    const float* hw     = (const float*)d_in[19];
    const float* hb     = (const float*)d_in[20];
    float* ws = (float*)d_ws;
    float* out = (float*)d_out;

    prep_k<<<257, 64, 0, stream>>>(embed, gwih, gwhh, gbih, qw, qb, kw, vw,
                                   lwih, lwhh, lbih, lbhh, hw, ws);
    for (int t = 0; t < LL; ++t) {
        step_k<<<BB, 64, 0, stream>>>(t, seq, memory, gbhh, vb, tw, tb, ws);
    }
    epi_k<<<BB, 64, 0, stream>>>(hb, ws, out);
}

// Round 4
// 4551.807 us; speedup vs baseline: 1.3112x; 1.3112x over previous
//
#include <hip/hip_runtime.h>
#include <math.h>

#define BB 1024
#define LL 256

// ws float offsets
#define OFF_TOKPROJ 0        // 64*192
#define OFF_A       12288    // 64*64
#define OFF_AVEC    16384    // 64
#define OFF_G       16448    // 64*192
#define OFF_CVEC    28736    // 192
#define OFF_HEADT   28928    // 64*64
#define OFF_ACC     33024    // 256 u64 (512 floats)
#define OFF_LEAF    33536    // 256*32 u64 (16384 floats)

#define MASK52 ((1ULL << 52) - 1)
#define THRESH (512ULL << 30)

// Bounded spin: in the healthy co-resident world the condition is met within
// microseconds; the bound (~2^18 iters) only fires if co-residency is broken,
// converting a hang into a diagnosable wrong answer.
#define SPIN_WAIT(addrp, vout)                                                 \
    do {                                                                       \
        if (broken) { vout = 0; break; }                                       \
        int _it = 0;                                                           \
        for (;;) {                                                             \
            vout = __hip_atomic_load((addrp), __ATOMIC_RELAXED,                \
                                     __HIP_MEMORY_SCOPE_AGENT);                \
            if ((vout >> 52) == 32) break;                                     \
            if (++_it > (1 << 18)) { broken = true; vout = 0; break; }         \
            __builtin_amdgcn_s_sleep(2);                                       \
        }                                                                      \
    } while (0)

__device__ __forceinline__ float sigf(float x) { return 1.f / (1.f + expf(-x)); }

// ---------------- prep: fused tables, zero counters ----------------
__global__ __launch_bounds__(64) void prep_k(
    const float* __restrict__ embed, const float* __restrict__ gwih,
    const float* __restrict__ gbih, const float* __restrict__ qw,
    const float* __restrict__ qb, const float* __restrict__ kw,
    const float* __restrict__ vw, const float* __restrict__ vb,
    const float* __restrict__ hw, float* __restrict__ ws)
{
    int blk = blockIdx.x, l = threadIdx.x;
    float* tokproj = ws + OFF_TOKPROJ;
    float* A = ws + OFF_A;
    float* avec = ws + OFF_AVEC;
    float* G = ws + OFF_G;
    float* cvec = ws + OFF_CVEC;
    float* headT = ws + OFF_HEADT;

    if (blk < 64) {
        int v = blk;
        for (int j = l; j < 192; j += 64) {
            float s = gbih[j];
            for (int d = 0; d < 64; ++d) s += embed[v * 64 + d] * gwih[j * 128 + d];
            tokproj[v * 192 + j] = s;
        }
    } else if (blk < 128) {
        int d = blk - 64;
        float s = 0.f;
        for (int e = 0; e < 64; ++e) s += qw[e * 64 + d] * kw[e * 64 + l];
        A[d * 64 + l] = s * 0.125f;
    } else if (blk < 192) {
        int e = blk - 128;
        for (int jj = 0; jj < 3; ++jj) {
            int j = jj * 64 + l;
            float s = 0.f;
            for (int d = 0; d < 64; ++d) s += vw[d * 64 + e] * gwih[j * 128 + 64 + d];
            G[e * 192 + j] = s;
        }
    } else if (blk == 192) {
        float s = 0.f;
        for (int e = 0; e < 64; ++e) s += qb[e] * kw[e * 64 + l];
        avec[l] = s * 0.125f;
        for (int jj = 0; jj < 3; ++jj) {
            int j = jj * 64 + l;
            float c = 0.f;
            for (int d = 0; d < 64; ++d) c += vb[d] * gwih[j * 128 + 64 + d];
            cvec[j] = c;
        }
    } else if (blk < 201) {
        int base = (blk - 193) * 2112;
        float* z = ws + OFF_ACC;
        for (int i = base + l; i < base + 2112; i += 64) z[i] = 0.f;
    } else {
        int d = blk - 201;
        headT[d * 64 + l] = hw[l * 64 + d];
    }
}

// ---------------- persistent kernel: all 256 steps ----------------
// __launch_bounds__(64,1): 1 wave/EU declared => 4 blocks/CU => grid 1024
// co-resident on 256 CUs (guide §1 contract). No grid.sync needed: the only
// cross-block dependency flows through the acc/leaf atomic rendezvous.
__global__ __launch_bounds__(64, 1) void persist_k(
    const int* __restrict__ seq, const float* __restrict__ memory,
    const float* __restrict__ gwhh, const float* __restrict__ gbhh,
    const float* __restrict__ lwih, const float* __restrict__ lwhh,
    const float* __restrict__ lbih, const float* __restrict__ lbhh,
    const float* __restrict__ tw, const float* __restrict__ tb,
    const float* __restrict__ hb, float* __restrict__ ws,
    float* __restrict__ out)
{
    int b = blockIdx.x, l = threadIdx.x;
    const float* tokproj = ws + OFF_TOKPROJ;
    const float* A = ws + OFF_A;
    const float* avec = ws + OFF_AVEC;
    const float* G = ws + OFF_G;
    const float* cvec = ws + OFF_CVEC;
    const float* headT = ws + OFF_HEADT;
    unsigned long long* acc = (unsigned long long*)(ws + OFF_ACC);
    unsigned long long* leaf = (unsigned long long*)(ws + OFF_LEAF);

    __shared__ float mch[32][65];
    __shared__ float lwhhT_s[32][128];
    __shared__ float hs[64], qs[64], us[64], wsm[32], hhs[32];
    __shared__ float PX[4][128];
    __shared__ int toks[256];

    bool broken = false;

    // ---- one-time staging ----
    for (int k = 0; k < 4; ++k) toks[k * 64 + l] = seq[b * 256 + k * 64 + l];
    for (int idx = l; idx < 4096; idx += 64) {
        int j = idx >> 5, d = idx & 31;
        lwhhT_s[d][j] = lwhh[idx];
    }

    float whh0[64], whh1[64], whh2[64], wl0[64], wl1[64];
    // gwhh: rows {l, 64+l, 128+l} via coalesced LDS bounce
    for (int c = 0; c < 6; ++c) {
        __syncthreads();
        for (int r = 0; r < 32; ++r) mch[r][l] = gwhh[(c * 32 + r) * 64 + l];
        __syncthreads();
        if ((l >> 5) == c) {
            #pragma unroll
            for (int d = 0; d < 64; ++d) whh0[d] = mch[l & 31][d];
        }
        if ((l >> 5) == c - 2) {
            #pragma unroll
            for (int d = 0; d < 64; ++d) whh1[d] = mch[l & 31][d];
        }
        if ((l >> 5) == c - 4) {
            #pragma unroll
            for (int d = 0; d < 64; ++d) whh2[d] = mch[l & 31][d];
        }
    }
    // lwih: rows {l, 64+l}
    for (int c = 0; c < 4; ++c) {
        __syncthreads();
        for (int r = 0; r < 32; ++r) mch[r][l] = lwih[(c * 32 + r) * 64 + l];
        __syncthreads();
        if ((l >> 5) == c) {
            #pragma unroll
            for (int d = 0; d < 64; ++d) wl0[d] = mch[l & 31][d];
        }
        if ((l >> 5) == c - 2) {
            #pragma unroll
            for (int d = 0; d < 64; ++d) wl1[d] = mch[l & 31][d];
        }
    }

    float g0b = gbhh[l], g1b = gbhh[64 + l], g2b = gbhh[128 + l];
    float lb0 = lbih[l] + lbhh[l], lb1 = lbih[64 + l] + lbhh[64 + l];
    float avr = avec[l];
    float cv0 = cvec[l], cv1 = cvec[64 + l], cv2 = cvec[128 + l];
    float twr = (l < 32) ? tw[l] : 0.f;
    float tb0 = tb[0];
    float h = 0.f;
    hs[l] = 0.f;
    int g = b >> 5;
    bool isagg = ((b & 31) == 0);
    const float* mrow = memory + (size_t)b * 16384;
    __syncthreads();

    for (int t = 0; t < 256; ++t) {
        // gh: independent of read flag
        float gh0 = g0b, gh1 = g1b, gh2 = g2b;
        #pragma unroll
        for (int d = 0; d < 64; ++d) {
            float s = hs[d];
            gh0 += s * whh0[d]; gh1 += s * whh1[d]; gh2 += s * whh2[d];
        }
        int tok = toks[t];
        const float* tp = tokproj + tok * 192;
        float gi0 = tp[l], gi1 = tp[64 + l], gi2 = tp[128 + l];

        if (t >= 4) {
            unsigned long long v;
            SPIN_WAIT(&acc[t - 1], v);
            if ((v & MASK52) > THRESH) {
                // attention on h_{t-1}
                float qk = avr;
                #pragma unroll
                for (int d = 0; d < 64; ++d) qk += hs[d] * A[d * 64 + l];
                qs[l] = qk;
                __syncthreads();
                float Mx = -1e30f, D = 0.f, u = 0.f;
                for (int c = 0; c < 8; ++c) {
                    __syncthreads();
                    for (int r = 0; r < 32; ++r) mch[r][l] = mrow[(c * 32 + r) * 64 + l];
                    __syncthreads();
                    int m = l & 31, dh = (l >> 5) * 32;
                    float s = 0.f;
                    #pragma unroll
                    for (int dd = 0; dd < 32; ++dd) s += qs[dh + dd] * mch[m][dh + dd];
                    s += __shfl_xor(s, 32);
                    float cm = s;
                    cm = fmaxf(cm, __shfl_xor(cm, 16)); cm = fmaxf(cm, __shfl_xor(cm, 8));
                    cm = fmaxf(cm, __shfl_xor(cm, 4));  cm = fmaxf(cm, __shfl_xor(cm, 2));
                    cm = fmaxf(cm, __shfl_xor(cm, 1));
                    float newM = fmaxf(Mx, cm);
                    float fac = expf(Mx - newM), w = expf(s - newM);
                    if (l < 32) wsm[l] = w;
                    float sw = w;
                    sw += __shfl_xor(sw, 16); sw += __shfl_xor(sw, 8);
                    sw += __shfl_xor(sw, 4);  sw += __shfl_xor(sw, 2);
                    sw += __shfl_xor(sw, 1);
                    D = D * fac + sw; u *= fac;
                    __syncthreads();
                    #pragma unroll
                    for (int m2 = 0; m2 < 32; ++m2) u += wsm[m2] * mch[m2][l];
                    Mx = newM;
                }
                u /= D;
                us[l] = u;
                __syncthreads();
                gi0 += cv0; gi1 += cv1; gi2 += cv2;
                #pragma unroll
                for (int e = 0; e < 64; ++e) {
                    float s2 = us[e];
                    gi0 += s2 * G[e * 192 + l];
                    gi1 += s2 * G[e * 192 + 64 + l];
                    gi2 += s2 * G[e * 192 + 128 + l];
                }
            }
        }

        // finish GRU
        float r_ = sigf(gi0 + gh0), z_ = sigf(gi1 + gh1);
        float n_ = tanhf(gi2 + r_ * gh2);
        float hn = (1.f - z_) * n_ + z_ * h;
        __syncthreads();
        h = hn;
        hs[l] = hn;
        __syncthreads();

        // LSTM input projection
        float p0 = lb0, p1 = lb1;
        #pragma unroll
        for (int d = 0; d < 64; ++d) {
            float s = hs[d];
            p0 += s * wl0[d]; p1 += s * wl1[d];
        }
        PX[t & 3][l] = p0; PX[t & 3][64 + l] = p1;

        if (t >= 3) {
            float hh = 0.f, cc = 0.f;
            #pragma unroll
            for (int k = 0; k < 4; ++k) {
                float q0, q1;
                if (k == 3) { q0 = p0; q1 = p1; }
                else { int slot = (t - 3 + k) & 3; q0 = PX[slot][l]; q1 = PX[slot][64 + l]; }
                if (k) {
                    #pragma unroll
                    for (int d = 0; d < 32; ++d) {
                        float s = hhs[d];
                        q0 += s * lwhhT_s[d][l];
                        q1 += s * lwhhT_s[d][64 + l];
                    }
                }
                float f_ = __shfl(q0, l + 32), o_ = __shfl(q1, l + 32);
                if (l < 32) {
                    float ig = sigf(q0), ff = sigf(f_), gg = tanhf(q1), oo = sigf(o_);
                    cc = ff * cc + ig * gg;
                    hh = oo * tanhf(cc);
                    hhs[l] = hh;
                }
                __syncthreads();
            }
            float pp = (l < 32) ? hh * twr : 0.f;
            for (int o = 32; o; o >>= 1) pp += __shfl_xor(pp, o);
            if (l == 0) {
                float prob = sigf(pp + tb0);
                unsigned long long q = (unsigned long long)llrint((double)prob * 1073741824.0);
                atomicAdd(&leaf[t * 32 + g], q + (1ULL << 52));
            }
            if (isagg && l == 0) {
                unsigned long long v;
                SPIN_WAIT(&leaf[t * 32 + g], v);
                atomicAdd(&acc[t], (v & MASK52) + (1ULL << 52));
            }
        }
    }

    // epilogue: logits
    float sL = hb[l];
    #pragma unroll
    for (int d = 0; d < 64; ++d) sL += hs[d] * headT[d * 64 + l];
    out[b * 64 + l] = sL;

    if (b == 0) {
        unsigned long long v;
        SPIN_WAIT(&acc[255], v);
        int cnt = 0;
        for (int k = 0; k < 4; ++k) {
            int tt = 3 + l + 64 * k;
            if (tt < 256) {
                unsigned long long vv = __hip_atomic_load(&acc[tt], __ATOMIC_RELAXED, __HIP_MEMORY_SCOPE_AGENT);
                cnt += ((vv & MASK52) > THRESH) ? 1 : 0;
            }
        }
        for (int o = 32; o; o >>= 1) cnt += __shfl_xor(cnt, o);
        if (l == 0) out[65536] = broken ? -1234.0f : (float)cnt / 256.f;
    }
}

extern "C" void kernel_launch(void* const* d_in, const int* in_sizes, int n_in,
                              void* d_out, int out_size, void* d_ws, size_t ws_size,
                              hipStream_t stream)
{
    const int*   seq    = (const int*)d_in[0];
    const float* memory = (const float*)d_in[1];
    const float* embed  = (const float*)d_in[2];
    const float* gwih   = (const float*)d_in[3];
    const float* gwhh   = (const float*)d_in[4];
    const float* gbih   = (const float*)d_in[5];
    const float* gbhh   = (const float*)d_in[6];
    const float* qw     = (const float*)d_in[7];
    const float* qb     = (const float*)d_in[8];
    const float* kw     = (const float*)d_in[9];
    // d_in[10] = k_b : cancels in softmax, unused
    const float* vw     = (const float*)d_in[11];
    const float* vb     = (const float*)d_in[12];
    const float* lwih   = (const float*)d_in[13];
    const float* lwhh   = (const float*)d_in[14];
    const float* lbih   = (const float*)d_in[15];
    const float* lbhh   = (const float*)d_in[16];
    const float* tw     = (const float*)d_in[17];
    const float* tb     = (const float*)d_in[18];
    const float* hw     = (const float*)d_in[19];
    const float* hb     = (const float*)d_in[20];
    float* ws = (float*)d_ws;
    float* out = (float*)d_out;

    prep_k<<<265, 64, 0, stream>>>(embed, gwih, gbih, qw, qb, kw, vw, vb, hw, ws);
    persist_k<<<1024, 64, 0, stream>>>(seq, memory, gwhh, gbhh, lwih, lwhh,
                                       lbih, lbhh, tw, tb, hb, ws, out);
}

// Round 5
// 2093.719 us; speedup vs baseline: 2.8506x; 2.1740x over previous
//
#include <hip/hip_runtime.h>
#include <math.h>

#define NBLK 256
#define TPB  256

// ws float offsets
#define OFF_TOKPROJ 0        // 64*192 = 12288
#define OFF_A       12288    // 64*64
#define OFF_AVEC    16384    // 64
#define OFF_G       16448    // 64*192
#define OFF_CVEC    28736    // 192
#define OFF_HEADT   28928    // 64*64
#define OFF_SLOTS   33024    // 256*256 u64 = 131072 floats

#define MASK44 ((1ULL << 44) - 1)
#define MARK   (1ULL << 44)
#define THRESH (512ULL << 30)   // mean > 0.5  <=>  sum(prob*2^30) > 512*2^30

__device__ __forceinline__ float sigf(float x) { return 1.f / (1.f + expf(-x)); }

// ---------------- prep: fused tables, zero slots ----------------
__global__ __launch_bounds__(64) void prep_k(
    const float* __restrict__ embed, const float* __restrict__ gwih,
    const float* __restrict__ gbih, const float* __restrict__ qw,
    const float* __restrict__ qb, const float* __restrict__ kw,
    const float* __restrict__ vw, const float* __restrict__ vb,
    const float* __restrict__ hw, float* __restrict__ ws)
{
    int blk = blockIdx.x, l = threadIdx.x;
    float* tokproj = ws + OFF_TOKPROJ;
    float* A = ws + OFF_A;
    float* avec = ws + OFF_AVEC;
    float* G = ws + OFF_G;
    float* cvec = ws + OFF_CVEC;
    float* headT = ws + OFF_HEADT;

    if (blk < 64) {
        int v = blk;
        for (int j = l; j < 192; j += 64) {
            float s = gbih[j];
            for (int d = 0; d < 64; ++d) s += embed[v * 64 + d] * gwih[j * 128 + d];
            tokproj[v * 192 + j] = s;
        }
    } else if (blk < 128) {
        int d = blk - 64;
        float s = 0.f;
        for (int e = 0; e < 64; ++e) s += qw[e * 64 + d] * kw[e * 64 + l];
        A[d * 64 + l] = s * 0.125f;   // 1/sqrt(64)
    } else if (blk < 192) {
        int e = blk - 128;
        for (int jj = 0; jj < 3; ++jj) {
            int j = jj * 64 + l;
            float s = 0.f;
            for (int d = 0; d < 64; ++d) s += vw[d * 64 + e] * gwih[j * 128 + 64 + d];
            G[e * 192 + j] = s;
        }
    } else if (blk == 192) {
        float s = 0.f;
        for (int e = 0; e < 64; ++e) s += qb[e] * kw[e * 64 + l];
        avec[l] = s * 0.125f;
        for (int jj = 0; jj < 3; ++jj) {
            int j = jj * 64 + l;
            float c = 0.f;
            for (int d = 0; d < 64; ++d) c += vb[d] * gwih[j * 128 + 64 + d];
            cvec[j] = c;
        }
    } else if (blk < 257) {
        int d = blk - 193;
        headT[d * 64 + l] = hw[l * 64 + d];
    } else {
        // zero the slot array (256 steps x 256 blocks x u64)
        float* z = ws + OFF_SLOTS;
        int base = (blk - 257) * 2048;
        for (int i = base + l; i < base + 2048; i += 64) z[i] = 0.f;
    }
}

// ---------------- persistent kernel: 4 rows/block, store-only rendezvous ----
__global__ __launch_bounds__(256, 1) void persist_k(
    const int* __restrict__ seq, const float* __restrict__ memory,
    const float* __restrict__ gwhh, const float* __restrict__ gbhh,
    const float* __restrict__ lwih, const float* __restrict__ lwhh,
    const float* __restrict__ lbih, const float* __restrict__ lbhh,
    const float* __restrict__ tw, const float* __restrict__ tb,
    const float* __restrict__ hb, float* __restrict__ ws,
    float* __restrict__ out)
{
    int tid = threadIdx.x;
    int w = tid >> 6, l = tid & 63;
    int b = blockIdx.x;
    int r = b * 4 + w;            // batch row owned by this wave

    const float* tokproj = ws + OFF_TOKPROJ;
    const float* A_ws = ws + OFF_A;
    const float* avec = ws + OFF_AVEC;
    const float* Gsrc = ws + OFF_G;
    const float* cvec = ws + OFF_CVEC;
    const float* headT = ws + OFF_HEADT;
    unsigned long long* slots = (unsigned long long*)(ws + OFF_SLOTS);

    __shared__ float mch[4][32][65];
    __shared__ float G_lds[12288];
    __shared__ float wlT[8192];
    __shared__ float lwhhT_s[32][128];
    __shared__ float hs[4][64], qs[4][64], us[4][64], wsm_s[4][32];
    __shared__ float PX[4][4][128];
    __shared__ int toks[4][256];
    __shared__ unsigned long long probq[4];
    __shared__ int flagLds;

    // ---- one-time cooperative staging ----
    for (int i = tid; i < 12288; i += TPB) G_lds[i] = Gsrc[i];
    for (int i = tid; i < 8192; i += TPB) {
        int d = i >> 7, j = i & 127;
        wlT[i] = lwih[j * 64 + d];                 // wlT[d*128 + j]
    }
    for (int i = tid; i < 4096; i += TPB) {
        int j = i >> 5, d = i & 31;
        lwhhT_s[d][j] = lwhh[i];                   // lwhh[j*32 + d]
    }
    for (int k = 0; k < 4; ++k) toks[w][k * 64 + l] = seq[r * 256 + k * 64 + l];
    if (tid == 0) flagLds = 0;

    // gwhh rows {l, 64+l, 128+l} -> registers, coalesced LDS bounce per wave
    float whh0[64], whh1[64], whh2[64];
    for (int c = 0; c < 6; ++c) {
        __syncthreads();
        for (int r2 = 0; r2 < 32; ++r2) mch[w][r2][l] = gwhh[(c * 32 + r2) * 64 + l];
        __syncthreads();
        if ((l >> 5) == c) {
            #pragma unroll
            for (int d = 0; d < 64; ++d) whh0[d] = mch[w][l & 31][d];
        }
        if ((l >> 5) == c - 2) {
            #pragma unroll
            for (int d = 0; d < 64; ++d) whh1[d] = mch[w][l & 31][d];
        }
        if ((l >> 5) == c - 4) {
            #pragma unroll
            for (int d = 0; d < 64; ++d) whh2[d] = mch[w][l & 31][d];
        }
    }

    float g0b = gbhh[l], g1b = gbhh[64 + l], g2b = gbhh[128 + l];
    float lb0 = lbih[l] + lbhh[l], lb1 = lbih[64 + l] + lbhh[64 + l];
    float avr = avec[l];
    float cv0 = cvec[l], cv1 = cvec[64 + l], cv2 = cvec[128 + l];
    float twr = (l < 32) ? tw[l] : 0.f;
    float tb0 = tb[0];
    float h = 0.f;
    hs[w][l] = 0.f;
    int cnt = 0;
    bool brk = false;
    const float* mrow = memory + (size_t)r * 16384;
    __syncthreads();

    for (int t = 0; t < 256; ++t) {
        // GRU h-projection (independent of read flag)
        float gh0 = g0b, gh1 = g1b, gh2 = g2b;
        #pragma unroll
        for (int d = 0; d < 64; ++d) {
            float s = hs[w][d];
            gh0 += s * whh0[d]; gh1 += s * whh1[d]; gh2 += s * whh2[d];
        }
        int tok = toks[w][t];
        const float* tp = tokproj + tok * 192;
        float gi0 = tp[l], gi1 = tp[64 + l], gi2 = tp[128 + l];

        bool flag = false;
        if (t >= 4) {
            if (w == 0) {
                const unsigned long long* sl = slots + (size_t)(t - 1) * 256;
                unsigned long long tot = 0;
                int it = 0, ok = 1;
                if (!brk) {
                    for (;;) {
                        unsigned long long v =
                            __hip_atomic_load(sl + l, __ATOMIC_RELAXED, __HIP_MEMORY_SCOPE_AGENT) +
                            __hip_atomic_load(sl + 64 + l, __ATOMIC_RELAXED, __HIP_MEMORY_SCOPE_AGENT) +
                            __hip_atomic_load(sl + 128 + l, __ATOMIC_RELAXED, __HIP_MEMORY_SCOPE_AGENT) +
                            __hip_atomic_load(sl + 192 + l, __ATOMIC_RELAXED, __HIP_MEMORY_SCOPE_AGENT);
                        tot = v;
                        #pragma unroll
                        for (int o = 32; o; o >>= 1) tot += __shfl_xor(tot, o);
                        if ((tot >> 44) == 256) break;
                        if (++it > (1 << 15)) { ok = 0; brk = true; break; }
                        __builtin_amdgcn_s_sleep(2);
                    }
                } else ok = 0;
                int f = ok && ((tot & MASK44) > THRESH);
                cnt += f;                          // wave-uniform
                if (l == 0) flagLds = f;
            }
            __syncthreads();
            flag = (flagLds != 0);
        }

        if (flag) {
            // attention on h_{t-1} (hs still holds it)
            float qk = avr;
            #pragma unroll
            for (int d = 0; d < 64; ++d) qk += hs[w][d] * A_ws[d * 64 + l];
            qs[w][l] = qk;
            __syncthreads();
            float Mx = -1e30f, D = 0.f, u = 0.f;
            for (int c = 0; c < 8; ++c) {
                __syncthreads();
                for (int r2 = 0; r2 < 32; ++r2) mch[w][r2][l] = mrow[(c * 32 + r2) * 64 + l];
                __syncthreads();
                int m = l & 31, dh = (l >> 5) * 32;
                float s = 0.f;
                #pragma unroll
                for (int dd = 0; dd < 32; ++dd) s += qs[w][dh + dd] * mch[w][m][dh + dd];
                s += __shfl_xor(s, 32);
                float cm = s;
                cm = fmaxf(cm, __shfl_xor(cm, 16)); cm = fmaxf(cm, __shfl_xor(cm, 8));
                cm = fmaxf(cm, __shfl_xor(cm, 4));  cm = fmaxf(cm, __shfl_xor(cm, 2));
                cm = fmaxf(cm, __shfl_xor(cm, 1));
                float newM = fmaxf(Mx, cm);
                float fac = expf(Mx - newM), wv = expf(s - newM);
                if (l < 32) wsm_s[w][l] = wv;
                float sw = wv;
                sw += __shfl_xor(sw, 16); sw += __shfl_xor(sw, 8);
                sw += __shfl_xor(sw, 4);  sw += __shfl_xor(sw, 2);
                sw += __shfl_xor(sw, 1);
                D = D * fac + sw; u *= fac;
                __syncthreads();
                #pragma unroll
                for (int m2 = 0; m2 < 32; ++m2) u += wsm_s[w][m2] * mch[w][m2][l];
                Mx = newM;
            }
            u /= D;
            us[w][l] = u;
            __syncthreads();
            gi0 += cv0; gi1 += cv1; gi2 += cv2;
            #pragma unroll
            for (int e = 0; e < 64; ++e) {
                float s2 = us[w][e];
                gi0 += s2 * G_lds[e * 192 + l];
                gi1 += s2 * G_lds[e * 192 + 64 + l];
                gi2 += s2 * G_lds[e * 192 + 128 + l];
            }
        }

        // finish GRU
        float r_ = sigf(gi0 + gh0), z_ = sigf(gi1 + gh1);
        float n_ = tanhf(gi2 + r_ * gh2);
        float hn = (1.f - z_) * n_ + z_ * h;
        __syncthreads();
        h = hn;
        hs[w][l] = hn;
        __syncthreads();

        // trigger-LSTM input projection for h_t (reused 4 steps)
        float p0 = lb0, p1 = lb1;
        #pragma unroll
        for (int d = 0; d < 64; ++d) {
            float s = hs[w][d];
            p0 += s * wlT[d * 128 + l];
            p1 += s * wlT[d * 128 + 64 + l];
        }
        PX[w][t & 3][l] = p0; PX[w][t & 3][64 + l] = p1;   // same-lane readback only

        if (t >= 3) {
            float hh = 0.f, cc = 0.f;                       // lanes 0..31 hold state
            #pragma unroll
            for (int k = 0; k < 4; ++k) {
                float q0, q1;
                if (k == 3) { q0 = p0; q1 = p1; }
                else { int sl2 = (t - 3 + k) & 3; q0 = PX[w][sl2][l]; q1 = PX[w][sl2][64 + l]; }
                if (k) {
                    #pragma unroll
                    for (int d = 0; d < 32; ++d) {
                        float s = __shfl(hh, d);            // broadcast lane d's state
                        q0 += s * lwhhT_s[d][l];
                        q1 += s * lwhhT_s[d][64 + l];
                    }
                }
                float f_ = __shfl(q0, l + 32), o_ = __shfl(q1, l + 32);
                float ig = sigf(q0), ff = sigf(f_), gg = tanhf(q1), oo = sigf(o_);
                float ncc = ff * cc + ig * gg;
                float nhh = oo * tanhf(ncc);
                if (l < 32) { cc = ncc; hh = nhh; }
            }
            float pp = (l < 32) ? hh * twr : 0.f;
            #pragma unroll
            for (int o = 32; o; o >>= 1) pp += __shfl_xor(pp, o);
            if (l == 0) {
                float prob = sigf(pp + tb0);
                probq[w] = (unsigned long long)llrint((double)prob * 1073741824.0);
            }
            __syncthreads();
            if (tid == 0) {
                unsigned long long sv = probq[0] + probq[1] + probq[2] + probq[3] + MARK;
                __hip_atomic_store(&slots[(size_t)t * 256 + b], sv,
                                   __ATOMIC_RELAXED, __HIP_MEMORY_SCOPE_AGENT);
            }
        }
    }

    // epilogue: logits
    float sL = hb[l];
    #pragma unroll
    for (int d = 0; d < 64; ++d) sL += hs[w][d] * headT[d * 64 + l];
    out[r * 64 + l] = sL;

    // read_rate: block 0 wave 0 also needs the final flag (t=255)
    if (b == 0 && w == 0) {
        const unsigned long long* sl = slots + (size_t)255 * 256;
        unsigned long long tot = 0;
        int it = 0, ok = 1;
        if (!brk) {
            for (;;) {
                unsigned long long v =
                    __hip_atomic_load(sl + l, __ATOMIC_RELAXED, __HIP_MEMORY_SCOPE_AGENT) +
                    __hip_atomic_load(sl + 64 + l, __ATOMIC_RELAXED, __HIP_MEMORY_SCOPE_AGENT) +
                    __hip_atomic_load(sl + 128 + l, __ATOMIC_RELAXED, __HIP_MEMORY_SCOPE_AGENT) +
                    __hip_atomic_load(sl + 192 + l, __ATOMIC_RELAXED, __HIP_MEMORY_SCOPE_AGENT);
                tot = v;
                #pragma unroll
                for (int o = 32; o; o >>= 1) tot += __shfl_xor(tot, o);
                if ((tot >> 44) == 256) break;
                if (++it > (1 << 15)) { ok = 0; brk = true; break; }
                __builtin_amdgcn_s_sleep(2);
            }
        } else ok = 0;
        cnt += (ok && ((tot & MASK44) > THRESH)) ? 1 : 0;
        if (l == 0) out[65536] = brk ? -1234.0f : (float)cnt / 256.f;
    }
}

extern "C" void kernel_launch(void* const* d_in, const int* in_sizes, int n_in,
                              void* d_out, int out_size, void* d_ws, size_t ws_size,
                              hipStream_t stream)
{
    const int*   seq    = (const int*)d_in[0];
    const float* memory = (const float*)d_in[1];
    const float* embed  = (const float*)d_in[2];
    const float* gwih   = (const float*)d_in[3];
    const float* gwhh   = (const float*)d_in[4];
    const float* gbih   = (const float*)d_in[5];
    const float* gbhh   = (const float*)d_in[6];
    const float* qw     = (const float*)d_in[7];
    const float* qb     = (const float*)d_in[8];
    const float* kw     = (const float*)d_in[9];
    // d_in[10] = k_b : cancels in softmax, unused
    const float* vw     = (const float*)d_in[11];
    const float* vb     = (const float*)d_in[12];
    const float* lwih   = (const float*)d_in[13];
    const float* lwhh   = (const float*)d_in[14];
    const float* lbih   = (const float*)d_in[15];
    const float* lbhh   = (const float*)d_in[16];
    const float* tw     = (const float*)d_in[17];
    const float* tb     = (const float*)d_in[18];
    const float* hw     = (const float*)d_in[19];
    const float* hb     = (const float*)d_in[20];
    float* ws = (float*)d_ws;
    float* out = (float*)d_out;

    prep_k<<<321, 64, 0, stream>>>(embed, gwih, gbih, qw, qb, kw, vw, vb, hw, ws);
    persist_k<<<NBLK, TPB, 0, stream>>>(seq, memory, gwhh, gbhh, lwih, lwhh,
                                        lbih, lbhh, tw, tb, hb, ws, out);
}